// Round 10
// baseline (2083.395 us; speedup 1.0000x reference)
//
#include <hip/hip_runtime.h>
#include <hip/hip_fp16.h>

#define B_   64
#define NB   128
#define E_   1024
#define DH   300
#define G3   900
#define OUTD 1924
#define SLICES 4
#define MROW 160    // u64/row: u32 data words [0..149], tag u64s [152..159]
#define WROW 152    // u32 per weight row in PK2T
#define GSTRIDE 912 // u16 row stride of f16 GIC1/GHP1

typedef _Float16 h2raw __attribute__((ext_vector_type(2)));

__device__ __forceinline__ float dot2f(unsigned int m2, unsigned int w, float acc) {
    h2raw a, b;
    __builtin_memcpy(&a, &m2, 4);
    __builtin_memcpy(&b, &w, 4);
    return __builtin_amdgcn_fdot2(a, b, acc, false);
}

__device__ __forceinline__ unsigned int packh2(float x, float y) {
    __half2 h;
    h.x = __float2half_rn(x);
    h.y = __float2half_rn(y);
    unsigned int u;
    __builtin_memcpy(&u, &h, 4);
    return u;
}

__device__ __forceinline__ float sigmoidf_(float x) { return 1.f / (1.f + __expf(-x)); }
__device__ __forceinline__ float tanh_fast(float x) { return 1.f - 2.f / (__expf(2.f * x) + 1.f); }

// ---------------- copy features into output tail ----------------
__global__ __launch_bounds__(256)
void copy_feat(const float* __restrict__ f, float* __restrict__ out) {
    const long id = (long)blockIdx.x * 256 + threadIdx.x;
    const long r = id >> 8;
    const int  c = (int)(id & 255);
    const float4 v = ((const float4*)(f + r * E_))[c];
    ((float4*)(out + r * OUTD + 3 * DH))[c] = v;
}

// ---------------- pack recurrent weights -> PK2T[l][R(1800)][152] row-contiguous f16-pairs ----------------
// R = mat*900 + o; mat0 = gc_whh (gh_c), mat1 = gp_wih (gi_p); kp<150: (W[o][2kp], W[o][2kp+1])
__global__ __launch_bounds__(256)
void pack2t(const float* __restrict__ gc_whh, const float* __restrict__ gp_wih,
            unsigned int* __restrict__ dst) {
    const int id = blockIdx.x * 256 + threadIdx.x;
    if (id >= 2 * 1800 * WROW) return;
    const int l   = id / (1800 * WROW);
    const int rem = id % (1800 * WROW);
    const int R   = rem / WROW;
    const int kp  = rem % WROW;
    unsigned int u = 0u;
    if (kp < 150) {
        const int mat = R / G3;
        const int o   = R % G3;
        const float* W = (mat ? gp_wih : gc_whh) + (long)l * G3 * DH;
        const float2 v = *(const float2*)(W + (long)o * DH + 2 * kp);
        u = packh2(v.x, v.y);
    }
    dst[id] = u;
}

// ---------------- GEMM input packing to f16 pairs ----------------
__global__ __launch_bounds__(256)
void pack_af(const float* __restrict__ src, unsigned int* __restrict__ dst) {
    const long id = (long)blockIdx.x * 256 + threadIdx.x;   // 8192*512
    const long r = id >> 9;
    const int kp = (int)(id & 511);
    const float2 v = *(const float2*)(src + r * E_ + 2 * kp);
    dst[id] = packh2(v.x, v.y);
}

__global__ __launch_bounds__(256)
void pack_ah(const float* __restrict__ src, unsigned int* __restrict__ dst) {
    const long id = (long)blockIdx.x * 256 + threadIdx.x;   // 8192*160
    const long r = id / 160;
    const int kp = (int)(id % 160);
    unsigned int u = 0u;
    if (kp < 150) {
        const float2 v = *(const float2*)(src + r * OUTD + 2 * kp);
        u = packh2(v.x, v.y);
    }
    dst[id] = u;
}

__global__ __launch_bounds__(256)
void pack_bf(const float* __restrict__ W, unsigned int* __restrict__ dst) {
    const int id = blockIdx.x * 256 + threadIdx.x;          // 320*512
    const int n = id >> 9;
    const int kp = id & 511;
    unsigned int u = 0u;
    if (n < DH) u = packh2(W[(2 * kp) * DH + n], W[(2 * kp + 1) * DH + n]);
    dst[id] = u;
}

__global__ __launch_bounds__(256)
void pack_bw(const float* __restrict__ W, unsigned int* __restrict__ dst) {
    const int id = blockIdx.x * 256 + threadIdx.x;          // 960*160
    const int n = id / 160;
    const int kp = id % 160;
    unsigned int u = 0u;
    if (n < G3 && kp < 150) {
        const float2 v = *(const float2*)(W + (long)n * DH + 2 * kp);
        u = packh2(v.x, v.y);
    }
    dst[id] = u;
}

// ---------------- f16-dot2 GEMM ----------------
template<int RELU>
__global__ __launch_bounds__(256)
void gemm_h16(const unsigned int* __restrict__ APK, int ldap,
              const unsigned int* __restrict__ BPK, int ldbp,
              const float* __restrict__ bias,
              float* __restrict__ C, int ldc,
              int N, int KP)
{
    __shared__ __align__(16) unsigned int As[16][132];
    __shared__ __align__(16) unsigned int Bs[16][68];
    const int tid = threadIdx.x;
    const int m0 = blockIdx.y * 128;
    const int n0 = blockIdx.x * 64;
    const int tx = tid & 15, ty = tid >> 4;
    const int am = tid >> 1, ak8 = (tid & 1) * 8;
    const int bn = tid >> 2, bk4 = (tid & 3) * 4;

    float acc[8][4] = {{0.f}};
    const unsigned int* ap = APK + (long)(m0 + am) * ldap + ak8;
    const unsigned int* bp = BPK + (long)(n0 + bn) * ldbp + bk4;

    for (int kp0 = 0; kp0 < KP; kp0 += 16) {
        const uint4 a0 = *(const uint4*)(ap + kp0);
        const uint4 a1 = *(const uint4*)(ap + kp0 + 4);
        const uint4 bq = *(const uint4*)(bp + kp0);
        As[ak8 + 0][am] = a0.x; As[ak8 + 1][am] = a0.y;
        As[ak8 + 2][am] = a0.z; As[ak8 + 3][am] = a0.w;
        As[ak8 + 4][am] = a1.x; As[ak8 + 5][am] = a1.y;
        As[ak8 + 6][am] = a1.z; As[ak8 + 7][am] = a1.w;
        Bs[bk4 + 0][bn] = bq.x; Bs[bk4 + 1][bn] = bq.y;
        Bs[bk4 + 2][bn] = bq.z; Bs[bk4 + 3][bn] = bq.w;
        __syncthreads();
        #pragma unroll
        for (int kp = 0; kp < 16; ++kp) {
            const uint4 aA = *(const uint4*)&As[kp][ty * 8];
            const uint4 aB = *(const uint4*)&As[kp][ty * 8 + 4];
            const uint4 bb = *(const uint4*)&Bs[kp][tx * 4];
            const unsigned int av[8] = {aA.x, aA.y, aA.z, aA.w, aB.x, aB.y, aB.z, aB.w};
            const unsigned int bv[4] = {bb.x, bb.y, bb.z, bb.w};
            #pragma unroll
            for (int ii = 0; ii < 8; ++ii)
                #pragma unroll
                for (int jj = 0; jj < 4; ++jj)
                    acc[ii][jj] = dot2f(av[ii], bv[jj], acc[ii][jj]);
        }
        __syncthreads();
    }

    const int gn0 = n0 + tx * 4;
    #pragma unroll
    for (int ii = 0; ii < 8; ++ii) {
        const int gm = m0 + ty * 8 + ii;
        float* cp = C + (long)gm * ldc + gn0;
        if (gn0 + 3 < N) {
            const float4 bb = *(const float4*)&bias[gn0];
            float4 o;
            o.x = acc[ii][0] + bb.x; o.y = acc[ii][1] + bb.y;
            o.z = acc[ii][2] + bb.z; o.w = acc[ii][3] + bb.w;
            if (RELU) { o.x = fmaxf(o.x, 0.f); o.y = fmaxf(o.y, 0.f); o.z = fmaxf(o.z, 0.f); o.w = fmaxf(o.w, 0.f); }
            *(float4*)cp = o;
        } else if (gn0 < N) {
            for (int jj = 0; jj < 4; ++jj) {
                const int gn = gn0 + jj;
                if (gn < N) {
                    float v = acc[ii][jj] + bias[gn];
                    if (RELU) v = fmaxf(v, 0.f);
                    cp[jj] = v;
                }
            }
        }
    }
}

// ---------------- DAG scan v10: true-VGPR weights + fused next-layer GEMM tail ----------------
__global__ __launch_bounds__(512)
void scan10(float* __restrict__ out,
            const float* __restrict__ GICf,      // layer-0 f32 gate inputs (l==0)
            const float* __restrict__ GHPf,
            const __half* __restrict__ GICh,     // layer-1 f16 gate inputs (l==1)
            const __half* __restrict__ GHPh,
            const unsigned int* __restrict__ PK2L,  // this layer: [1800][152] row-contiguous
            const float* __restrict__ cbhh,
            const float* __restrict__ pbih,
            const int* __restrict__ adj,
            const float* __restrict__ wk,
            unsigned long long* __restrict__ TBL,
            int l,
            int do_tail,
            const unsigned int* __restrict__ BW1c,  // layer-1 cwih packed [900][160]
            const unsigned int* __restrict__ BW1p,  // layer-1 pwhh packed [900][160]
            const float* __restrict__ bih1,
            const float* __restrict__ bhh1,
            __half* __restrict__ G1C,               // f16 out [8192][912]
            __half* __restrict__ G1P)
{
    extern __shared__ unsigned int histp[];   // [128][152] f16-pairs
    __shared__ float wsm2[NB];
    __shared__ float betas[NB];
    __shared__ float Mlds[DH];
    __shared__ __align__(16) unsigned int M2[152];
    __shared__ float gmv[456];
    __shared__ float mx2s, S_pres;

    const int tid = threadIdx.x;
    const int lane = tid & 63;
    const int wid = tid >> 6;
    const int b = blockIdx.x & 63;
    const int k = blockIdx.x >> 6;
    const int swk = (k == 3) ? 72 : 76;

    float* outb = out + (long)b * NB * OUTD;
    const float* xcol = outb + l * DH;
    float* ycol = outb + (l + 1) * DH;
    const int* adjb = adj + b * NB * NB;
    unsigned long long* mb = TBL + (long)b * NB * MROW;
    unsigned int* mb32 = (unsigned int*)mb;

    if (tid < 152) M2[tid] = 0u;

    const int D = 76 * k + ((tid < swk) ? tid : 0);
    const float cb0 = cbhh[D], cb1 = cbhh[DH + D], cb2 = cbhh[2 * DH + D];
    const float pb0 = pbih[D], pb1 = pbih[DH + D], pb2 = pbih[2 * DH + D];
    const float wkD = wk[D];

    const int ROWS = 6 * swk;
    int R;
    {
        const int t = (tid < ROWS) ? tid : 0;
        const int d = t % swk;
        const int r = t / swk;
        R = (r / 3) * G3 + (r % 3) * DH + 76 * k + d;
    }
    // weight row: contiguous 38 uint4 loads, explicit registers
    uint4 wv[38];
    {
        const unsigned int* wrow = PK2L + (long)R * WROW;
        #pragma unroll
        for (int q = 0; q < 38; ++q) wv[q] = *(const uint4*)(wrow + 4 * q);
    }

    __syncthreads();

    const bool isv = (tid >= 256) && (tid < 406);
    const int vt = tid - 256;

    for (int i = 0; i < NB; ++i) {
        // ---- top-of-step prefetches ----
        float gi0 = 0, gi1 = 0, gi2 = 0, gp0 = 0, gp1 = 0, gp2 = 0, xi = 0;
        if (tid < swk) {
            if (l == 0) {
                const float* gic = GICf + ((long)b * NB + i) * G3;
                const float* ghp = GHPf + ((long)b * NB + i) * G3;
                gi0 = gic[D]; gi1 = gic[DH + D]; gi2 = gic[2 * DH + D];
                gp0 = ghp[D]; gp1 = ghp[DH + D]; gp2 = ghp[2 * DH + D];
            } else {
                const __half* gic = GICh + ((long)b * NB + i) * GSTRIDE;
                const __half* ghp = GHPh + ((long)b * NB + i) * GSTRIDE;
                gi0 = __half2float(gic[D]); gi1 = __half2float(gic[DH + D]); gi2 = __half2float(gic[2 * DH + D]);
                gp0 = __half2float(ghp[D]); gp1 = __half2float(ghp[DH + D]); gp2 = __half2float(ghp[2 * DH + D]);
            }
            xi = xcol[(long)i * OUTD + D];
        }
        int a0p = 0, a1p = 0;
        if (wid == 2 && i + 1 < NB) {
            a0p = adjb[(i + 1) * NB + lane];
            a1p = adjb[(i + 1) * NB + 64 + lane];
        }

        if (i > 0) {
            float V0 = 0.f, V1 = 0.f;
            if (wid == 0) {
                // ---- poll 8 self-describing tag words ----
                const unsigned long long* trow = mb + (long)(i - 1) * MROW;
                const unsigned int tag = (unsigned int)i;
                const bool act = (lane < 8);
                unsigned long long tv = 0;
                while (true) {
                    if (act && (unsigned int)tv != tag)
                        tv = __hip_atomic_load(&trow[152 + lane],
                                               __ATOMIC_RELAXED, __HIP_MEMORY_SCOPE_AGENT);
                    if (__all(!act || (unsigned int)tv == tag)) break;
                }
                float bp = 0.f;
                if (act) {
                    const unsigned int hb = (unsigned int)(tv >> 32);
                    __builtin_memcpy(&bp, &hb, 4);
                }
                bp += __shfl_xor(bp, 1);
                bp += __shfl_xor(bp, 2);
                bp += __shfl_xor(bp, 4);
                if (lane == 0) betas[i - 1] = __shfl(bp, 0);

                unsigned long long d0 = 0, d1 = 0;
                if (lane < 38) {
                    d0 = __hip_atomic_load(&trow[2 * lane],
                                           __ATOMIC_RELAXED, __HIP_MEMORY_SCOPE_AGENT);
                    d1 = __hip_atomic_load(&trow[2 * lane + 1],
                                           __ATOMIC_RELAXED, __HIP_MEMORY_SCOPE_AGENT);
                    uint4 q;
                    q.x = (unsigned int)d0; q.y = (unsigned int)(d0 >> 32);
                    q.z = (unsigned int)d1; q.w = (unsigned int)(d1 >> 32);
                    *(uint4*)&histp[(i - 1) * 152 + 4 * lane] = q;
                }
            } else if (isv) {
                // ---- V-loop over j <= i-2 with precomputed unnormalized weights ----
                #pragma unroll 4
                for (int j = 0; j + 1 < i; ++j) {
                    const float wj = wsm2[j];
                    const unsigned int u = histp[j * 152 + vt];
                    __half2 h; __builtin_memcpy(&h, &u, 4);
                    V0 = fmaf(wj, __half2float(h.x), V0);
                    V1 = fmaf(wj, __half2float(h.y), V1);
                }
            }
            __syncthreads();   // B1

            if (isv) {
                const float beta_new = betas[i - 1];
                const float mxl = mx2s;
                float S = S_pres, e;
                if (beta_new > mxl) {
                    const float sc = __expf(mxl - beta_new);
                    V0 *= sc; V1 *= sc; S *= sc; e = 1.f;
                } else {
                    e = __expf(beta_new - mxl);
                }
                const unsigned int u = histp[(i - 1) * 152 + vt];
                __half2 h; __builtin_memcpy(&h, &u, 4);
                S += e;
                V0 = fmaf(e, __half2float(h.x), V0);
                V1 = fmaf(e, __half2float(h.y), V1);
                const float inv = 1.f / S;
                const float m0 = V0 * inv, m1 = V1 * inv;
                Mlds[2 * vt] = m0;
                Mlds[2 * vt + 1] = m1;
                M2[vt] = packh2(m0, m1);
            }
        } else {
            if (tid < DH) Mlds[tid] = 0.f;
        }
        __syncthreads();   // B4

        // ---- matvec from true register weights ----
        if (tid < ROWS) {
            float a0 = 0.f, a1 = 0.f;
            #pragma unroll
            for (int q = 0; q < 38; ++q) {
                const uint4 m4 = *(const uint4*)&M2[4 * q];
                a0 = dot2f(m4.x, wv[q].x, a0);
                a1 = dot2f(m4.y, wv[q].y, a1);
                a0 = dot2f(m4.z, wv[q].z, a0);
                a1 = dot2f(m4.w, wv[q].w, a1);
            }
            gmv[tid] = a0 + a1;
        }
        __syncthreads();   // B5

        // ---- gates + per-wave early release (waves 0-1) || prep next softmax (wave 2) ----
        if (wid < 2) {
            float rowv = 0.f;
            if (tid < swk) {
                const float Mi = Mlds[D];
                const float hc0 = gmv[0 * swk + tid] + cb0;
                const float hc1 = gmv[1 * swk + tid] + cb1;
                const float hc2 = gmv[2 * swk + tid] + cb2;
                const float rc = sigmoidf_(gi0 + hc0);
                const float zc = sigmoidf_(gi1 + hc1);
                const float nc = tanh_fast(gi2 + rc * hc2);
                const float Cc = (1.f - zc) * nc + zc * Mi;
                const float ip0 = gmv[3 * swk + tid] + pb0;
                const float ip1 = gmv[4 * swk + tid] + pb1;
                const float ip2 = gmv[5 * swk + tid] + pb2;
                const float rp = sigmoidf_(ip0 + gp0);
                const float zp = sigmoidf_(ip1 + gp1);
                const float np = tanh_fast(ip2 + rp * gp2);
                const float Pp = (1.f - zp) * np + zp * xi;
                rowv = Cc + Pp;
            }
            const float pr = __shfl_xor(rowv, 1);
            const unsigned int pairu32 = packh2(rowv, pr);
            if (tid < swk && !(tid & 1)) {
                __hip_atomic_store(&mb32[(long)i * (MROW * 2) + 38 * k + (tid >> 1)], pairu32,
                                   __ATOMIC_RELAXED, __HIP_MEMORY_SCOPE_AGENT);
            }
            float bv = (tid < swk) ? rowv * wkD : 0.f;
            #pragma unroll
            for (int off = 32; off; off >>= 1) bv += __shfl_xor(bv, off);
            asm volatile("s_waitcnt vmcnt(0)" ::: "memory");
            if (lane == 0) {
                unsigned int bbits;
                __builtin_memcpy(&bbits, &bv, 4);
                const unsigned long long pkt =
                    ((unsigned long long)bbits << 32) | (unsigned int)(i + 1);
                __hip_atomic_store(&mb[(long)i * MROW + 152 + 2 * k + wid], pkt,
                                   __ATOMIC_RELAXED, __HIP_MEMORY_SCOPE_AGENT);
            }
            if (tid < swk) ycol[(long)i * OUTD + D] = rowv;
        } else if (wid == 2 && i + 1 < NB) {
            const int j1 = lane + 64;
            const bool v0 = (lane < i) && (a0p != 0);
            const bool v1 = (j1 < i) && (a1p != 0);
            const float aa0 = v0 ? betas[lane] : -3.0e38f;
            const float aa1 = v1 ? betas[j1]   : -3.0e38f;
            float mx = fmaxf(aa0, aa1);
            #pragma unroll
            for (int off = 32; off; off >>= 1) mx = fmaxf(mx, __shfl_xor(mx, off));
            const float e0 = v0 ? __expf(aa0 - mx) : 0.f;
            const float e1 = v1 ? __expf(aa1 - mx) : 0.f;
            float s = e0 + e1;
            #pragma unroll
            for (int off = 32; off; off >>= 1) s += __shfl_xor(s, off);
            wsm2[lane] = e0;
            wsm2[j1]   = e1;
            if (lane == 0) { mx2s = mx; S_pres = s; }
        }
        __syncthreads();   // B6
    }

    // ================= fused layer-1 gate-input GEMM tail (l==0 only) =================
    if (do_tail) {
        // ingest row 127 into history (poll its tags, load data)
        if (wid == 0) {
            const unsigned long long* trow = mb + 127L * MROW;
            const unsigned int tag = 128u;
            const bool act = (lane < 8);
            unsigned long long tv = 0;
            while (true) {
                if (act && (unsigned int)tv != tag)
                    tv = __hip_atomic_load(&trow[152 + lane],
                                           __ATOMIC_RELAXED, __HIP_MEMORY_SCOPE_AGENT);
                if (__all(!act || (unsigned int)tv == tag)) break;
            }
            if (lane < 38) {
                const unsigned long long d0 = __hip_atomic_load(&trow[2 * lane],
                                                  __ATOMIC_RELAXED, __HIP_MEMORY_SCOPE_AGENT);
                const unsigned long long d1 = __hip_atomic_load(&trow[2 * lane + 1],
                                                  __ATOMIC_RELAXED, __HIP_MEMORY_SCOPE_AGENT);
                uint4 q;
                q.x = (unsigned int)d0; q.y = (unsigned int)(d0 >> 32);
                q.z = (unsigned int)d1; q.w = (unsigned int)(d1 >> 32);
                *(uint4*)&histp[127 * 152 + 4 * lane] = q;
            }
        }
        __syncthreads();

        // each thread owns (mat, n) in this block's quarter; B row in registers
        if (tid < 450) {
            const int mat = tid / 225;
            const int n = 225 * k + (tid % 225);
            const unsigned int* brow = (mat ? BW1p : BW1c) + (long)n * 160;
            uint4 bv[38];
            #pragma unroll
            for (int q = 0; q < 38; ++q) bv[q] = *(const uint4*)(brow + 4 * q);
            const float bias = (mat ? bhh1 : bih1)[n];
            __half* dsth = (mat ? G1P : G1C) + (long)b * NB * GSTRIDE + n;
            for (int i = 0; i < NB; ++i) {
                float a0 = 0.f, a1 = 0.f;
                const unsigned int* arow = &histp[i * 152];
                #pragma unroll
                for (int q = 0; q < 38; ++q) {
                    const uint4 m4 = *(const uint4*)(arow + 4 * q);
                    a0 = dot2f(m4.x, bv[q].x, a0);
                    a1 = dot2f(m4.y, bv[q].y, a1);
                    a0 = dot2f(m4.z, bv[q].z, a0);
                    a1 = dot2f(m4.w, bv[q].w, a1);
                }
                dsth[(long)i * GSTRIDE] = __float2half_rn(a0 + a1 + bias);
            }
        }
    }
}

extern "C" void kernel_launch(void* const* d_in, const int* in_sizes, int n_in,
                              void* d_out, int out_size, void* d_ws, size_t ws_size,
                              hipStream_t stream) {
    (void)in_sizes; (void)n_in; (void)out_size; (void)ws_size;
    const float* features = (const float*)d_in[0];
    const float* fc1_w    = (const float*)d_in[1];
    const float* fc1_b    = (const float*)d_in[2];
    const float* gat_w    = (const float*)d_in[3];
    const float* gc_wih   = (const float*)d_in[5];
    const float* gc_whh   = (const float*)d_in[6];
    const float* gc_bih   = (const float*)d_in[7];
    const float* gc_bhh   = (const float*)d_in[8];
    const float* gp_wih   = (const float*)d_in[9];
    const float* gp_whh   = (const float*)d_in[10];
    const float* gp_bih   = (const float*)d_in[11];
    const float* gp_bhh   = (const float*)d_in[12];
    const int*   adj      = (const int*)d_in[13];
    float* out = (float*)d_out;

    unsigned long long* TB = (unsigned long long*)d_ws;             // 2*64*128*160 u64
    float* GIC = (float*)(TB + 2L * B_ * NB * MROW);                // 8192*900 f32
    float* GHP = GIC + (long)B_ * NB * G3;                          // 8192*900 f32
    unsigned int* PK2T = (unsigned int*)(GHP + (long)B_ * NB * G3); // 2*1800*152
    unsigned int* APK2 = PK2T + 2 * 1800 * WROW;                    // 8192*160
    unsigned int* BPKF = APK2 + 8192L * 160;                        // 320*512
    unsigned int* BPKL = BPKF + 320L * 512;                         // 4*960*160
    __half* G1C = (__half*)(BPKL + 4L * 960 * 160);                 // 8192*912 f16
    __half* G1P = G1C + 8192L * GSTRIDE;                            // 8192*912 f16
    unsigned int* APK1 = (unsigned int*)GIC;                        // alias

    hipFuncSetAttribute(reinterpret_cast<const void*>(scan10),
                        hipFuncAttributeMaxDynamicSharedMemorySize, 80000);
    hipMemsetAsync(TB, 0, 2L * B_ * NB * MROW * sizeof(unsigned long long), stream);

    copy_feat<<<dim3((B_ * NB * E_) / 1024), 256, 0, stream>>>(features, out);
    pack2t<<<dim3((2 * 1800 * WROW + 255) / 256), 256, 0, stream>>>(gc_whh, gp_wih, PK2T);

    pack_af<<<dim3(8192 * 512 / 256), 256, 0, stream>>>(features, APK1);
    pack_bf<<<dim3(320 * 512 / 256), 256, 0, stream>>>(fc1_w, BPKF);
    pack_bw<<<dim3(960 * 160 / 256), 256, 0, stream>>>(gc_wih,           BPKL + 0L * 153600);
    pack_bw<<<dim3(960 * 160 / 256), 256, 0, stream>>>(gp_whh,           BPKL + 1L * 153600);
    pack_bw<<<dim3(960 * 160 / 256), 256, 0, stream>>>(gc_wih + G3 * DH, BPKL + 2L * 153600);
    pack_bw<<<dim3(960 * 160 / 256), 256, 0, stream>>>(gp_whh + G3 * DH, BPKL + 3L * 153600);

    // H0 = relu(features @ fc1_w + b) -> out cols [0,300)
    gemm_h16<1><<<dim3(5, 64), 256, 0, stream>>>(APK1, 512, BPKF, 512, fc1_b, out, OUTD, DH, 512);

    // layer-0 gate-input GEMMs (f32 out)
    pack_ah<<<dim3(8192 * 160 / 256), 256, 0, stream>>>(out, APK2);
    gemm_h16<0><<<dim3(15, 64), 256, 0, stream>>>(
        APK2, 160, BPKL + 0L * 153600, 160, gc_bih, GIC, G3, G3, 160);
    gemm_h16<0><<<dim3(15, 64), 256, 0, stream>>>(
        APK2, 160, BPKL + 1L * 153600, 160, gp_bhh, GHP, G3, G3, 160);

    // scan layer 0 (+ fused layer-1 gate-input GEMM tail)
    scan10<<<dim3(SLICES * B_), 512, 77824, stream>>>(
        out, GIC, GHP, (const __half*)nullptr, (const __half*)nullptr,
        PK2T + 0L * 1800 * WROW,
        gc_bhh, gp_bih, adj, gat_w + DH,
        TB, 0, 1,
        BPKL + 2L * 153600, BPKL + 3L * 153600,
        gc_bih + G3, gp_bhh + G3, G1C, G1P);

    // scan layer 1 (reads f16 gate inputs; no tail)
    scan10<<<dim3(SLICES * B_), 512, 77824, stream>>>(
        out, (const float*)nullptr, (const float*)nullptr, G1C, G1P,
        PK2T + 1L * 1800 * WROW,
        gc_bhh + G3, gp_bih + G3, adj, gat_w + 3 * DH,
        TB + (long)B_ * NB * MROW, 1, 0,
        (const unsigned int*)nullptr, (const unsigned int*)nullptr,
        (const float*)nullptr, (const float*)nullptr,
        (__half*)nullptr, (__half*)nullptr);
}